// Round 6
// baseline (166.207 us; speedup 1.0000x reference)
//
#include <hip/hip_runtime.h>
#include <hip/hip_bf16.h>

typedef __attribute__((ext_vector_type(4))) float f32x4;
typedef __attribute__((ext_vector_type(8))) __bf16 bf16x8;

#define NCTX 8192
#define DH 128
#define ROWE 4096                    /* floats between consecutive positions */
#define SC2 0.12751705766482797f     /* (1/sqrt(128)) * log2(e) */
#define PSTR 40                      /* P lds row stride (bf16) */

// Pinned-register async loads: volatile asm keeps issue order and forces the
// allocator to hold every result live -> true memory-level parallelism.
#define GLOAD4(dst, ptr, off) \
  asm volatile("global_load_dwordx4 %0, %1, off offset:" #off : "=v"(dst) : "v"(ptr))
#define GLOAD1(dst, ptr, off) \
  asm volatile("global_load_dword %0, %1, off offset:" #off : "=v"(dst) : "v"(ptr))

__device__ __forceinline__ unsigned f2bf(float x) {
  union { float f; unsigned u; } un; un.f = x;
  return (un.u + 0x7FFFu + ((un.u >> 16) & 1u)) >> 16;   // RNE f32->bf16 bits
}
__device__ __forceinline__ unsigned pk2(float a, float b) {
  float2 t; t.x = a; t.y = b;
  union { __hip_bfloat162 h; unsigned u; } un;
  un.h = __float22bfloat162_rn(t);
  return un.u;
}
__device__ __forceinline__ bf16x8 mk8(f32x4 x, f32x4 y) {
  union { unsigned u[4]; bf16x8 f; } un;
  un.u[0] = pk2(x[0], x[1]); un.u[1] = pk2(x[2], x[3]);
  un.u[2] = pk2(y[0], y[1]); un.u[3] = pk2(y[2], y[3]);
  return un.f;
}

// One wave per position: 32(heads) x 32(heads) attention, d=128.
// All 96 loads of a position issued before the first dependent wait.
__global__ __launch_bounds__(256, 1) void hda(
    const float* __restrict__ q, const float* __restrict__ kg,
    const float* __restrict__ v, float* __restrict__ out)
{
  __shared__ __align__(16) unsigned short Pl[4][32][PSTR];  // per-wave P (bf16)

  const int tid  = threadIdx.x;
  const int w    = tid >> 6;
  const int lane = tid & 63;
  const int c = lane & 15;    // frag row/col index
  const int g = lane >> 4;    // lane group 0..3

  const int pos = blockIdx.x * 4 + w;     // 0..16383
  const int b = pos >> 13;
  const int s = pos & (NCTX - 1);
  const int r = min(4 * s, NCTX - 1);     // dilated + clamped K/V position

  const float* qp = q  + ((size_t)b * NCTX + s) * ROWE;
  const float* kp = kg + ((size_t)b * NCTX + r) * ROWE;
  const float* vp = v  + ((size_t)b * NCTX + r) * ROWE;
  float*       op = out + ((size_t)b * NCTX + s) * ROWE;

  // ---- issue ALL Q/K loads: 32x dwordx4 (rows c and 16+c, 8 frag-halves each)
  const float* bq0 = qp + c*DH + g*8;
  const float* bq1 = bq0 + 16*DH;
  const float* bk0 = kp + c*DH + g*8;
  const float* bk1 = bk0 + 16*DH;

  f32x4 qr[16], kr[16];
  GLOAD4(qr[0],  bq0, 0);   GLOAD4(qr[1],  bq0, 16);
  GLOAD4(qr[2],  bq0, 128); GLOAD4(qr[3],  bq0, 144);
  GLOAD4(qr[4],  bq0, 256); GLOAD4(qr[5],  bq0, 272);
  GLOAD4(qr[6],  bq0, 384); GLOAD4(qr[7],  bq0, 400);
  GLOAD4(qr[8],  bq1, 0);   GLOAD4(qr[9],  bq1, 16);
  GLOAD4(qr[10], bq1, 128); GLOAD4(qr[11], bq1, 144);
  GLOAD4(qr[12], bq1, 256); GLOAD4(qr[13], bq1, 272);
  GLOAD4(qr[14], bq1, 384); GLOAD4(qr[15], bq1, 400);
  GLOAD4(kr[0],  bk0, 0);   GLOAD4(kr[1],  bk0, 16);
  GLOAD4(kr[2],  bk0, 128); GLOAD4(kr[3],  bk0, 144);
  GLOAD4(kr[4],  bk0, 256); GLOAD4(kr[5],  bk0, 272);
  GLOAD4(kr[6],  bk0, 384); GLOAD4(kr[7],  bk0, 400);
  GLOAD4(kr[8],  bk1, 0);   GLOAD4(kr[9],  bk1, 16);
  GLOAD4(kr[10], bk1, 128); GLOAD4(kr[11], bk1, 144);
  GLOAD4(kr[12], bk1, 256); GLOAD4(kr[13], bk1, 272);
  GLOAD4(kr[14], bk1, 384); GLOAD4(kr[15], bk1, 400);

  // ---- issue ALL V loads: 64 scalar dwords, vv[j][dt] = V[g*8+j][dt*16+c]
  float vv[8][8];
#define VROW(j) do { const float* bv = vp + ((g*8+(j))*DH) + c; \
  GLOAD1(vv[(j)][0], bv, 0);   GLOAD1(vv[(j)][1], bv, 64);  \
  GLOAD1(vv[(j)][2], bv, 128); GLOAD1(vv[(j)][3], bv, 192); \
  GLOAD1(vv[(j)][4], bv, 256); GLOAD1(vv[(j)][5], bv, 320); \
  GLOAD1(vv[(j)][6], bv, 384); GLOAD1(vv[(j)][7], bv, 448); } while (0)
  VROW(0); VROW(1); VROW(2); VROW(3); VROW(4); VROW(5); VROW(6); VROW(7);
#undef VROW

  // ---- wait until <=32 outstanding: all 32 QK loads (+32 V) returned
  asm volatile("s_waitcnt vmcnt(32)" ::: "memory");
  __builtin_amdgcn_sched_barrier(0);

  bf16x8 qa[2][4], kf[2][4];
#pragma unroll
  for (int t = 0; t < 2; ++t)
#pragma unroll
    for (int ks = 0; ks < 4; ++ks) {
      qa[t][ks] = mk8(qr[t*8 + ks*2], qr[t*8 + ks*2 + 1]);
      kf[t][ks] = mk8(kr[t*8 + ks*2], kr[t*8 + ks*2 + 1]);
    }

  // ---- S = Q K^T over heads: 4 16x16 tiles, K-dim 128
  f32x4 S[2][2];
#pragma unroll
  for (int it = 0; it < 2; ++it)
#pragma unroll
    for (int jt = 0; jt < 2; ++jt) {
      f32x4 acc = (f32x4)0.0f;
#pragma unroll
      for (int ks = 0; ks < 4; ++ks)
        acc = __builtin_amdgcn_mfma_f32_16x16x32_bf16(qa[it][ks], kf[jt][ks], acc, 0, 0, 0);
      S[it][jt] = acc;
    }

  // D-layout: S[it][jt][rr] = S_full[it*16+g*4+rr][jt*16+c]
  // ---- softmax over 32 cols, no max-sub (scores ~N(0,1): exp2 arg small)
  float p[2][2][4], inv[2][4];
#pragma unroll
  for (int it = 0; it < 2; ++it) {
    float ls[4] = {0.f, 0.f, 0.f, 0.f};
#pragma unroll
    for (int jt = 0; jt < 2; ++jt)
#pragma unroll
      for (int rr = 0; rr < 4; ++rr) {
        float e = exp2f(S[it][jt][rr] * SC2);
        p[it][jt][rr] = e;
        ls[rr] += e;
      }
#pragma unroll
    for (int m = 1; m <= 8; m <<= 1)
#pragma unroll
      for (int rr = 0; rr < 4; ++rr)
        ls[rr] += __shfl_xor(ls[rr], m);
#pragma unroll
    for (int rr = 0; rr < 4; ++rr) inv[it][rr] = 1.0f / ls[rr];
  }

  // ---- normalized P -> per-wave LDS (row-major [i][j]), read back as frags
#pragma unroll
  for (int it = 0; it < 2; ++it)
#pragma unroll
    for (int jt = 0; jt < 2; ++jt)
#pragma unroll
      for (int rr = 0; rr < 4; ++rr)
        Pl[w][it*16 + g*4 + rr][jt*16 + c] =
            (unsigned short)f2bf(p[it][jt][rr] * inv[it][rr]);

  bf16x8 pa[2];   // lane holds P[it*16+c][g*8 ..+7] (A-frag == B-frag of P^T)
  pa[0] = *reinterpret_cast<const bf16x8*>(&Pl[w][c][g*8]);
  pa[1] = *reinterpret_cast<const bf16x8*>(&Pl[w][16 + c][g*8]);

  // ---- wait for V, then O^T = V^T P^T; float4 stores
  asm volatile("s_waitcnt vmcnt(0)" ::: "memory");
  __builtin_amdgcn_sched_barrier(0);

#pragma unroll
  for (int dt = 0; dt < 8; ++dt) {
    union { unsigned u[4]; bf16x8 f; } un;
    un.u[0] = pk2(vv[0][dt], vv[1][dt]); un.u[1] = pk2(vv[2][dt], vv[3][dt]);
    un.u[2] = pk2(vv[4][dt], vv[5][dt]); un.u[3] = pk2(vv[6][dt], vv[7][dt]);
#pragma unroll
    for (int it = 0; it < 2; ++it) {
      f32x4 o = __builtin_amdgcn_mfma_f32_16x16x32_bf16(un.f, pa[it], (f32x4)0.0f, 0, 0, 0);
      *reinterpret_cast<f32x4*>(op + (it*16 + c)*DH + dt*16 + g*4) = o;
    }
  }
}

extern "C" void kernel_launch(void* const* d_in, const int* in_sizes, int n_in,
                              void* d_out, int out_size, void* d_ws, size_t ws_size,
                              hipStream_t stream) {
  const float* q = (const float*)d_in[0];
  const float* k = (const float*)d_in[1];
  const float* v = (const float*)d_in[2];
  float* o = (float*)d_out;
  // 16384 positions (b=2 x s=8192), 4 waves/block -> 4096 blocks
  hda<<<dim3(4096, 1, 1), dim3(256, 1, 1), 0, stream>>>(q, k, v, o);
}

// Round 7
// 130.843 us; speedup vs baseline: 1.2703x; 1.2703x over previous
//
#include <hip/hip_runtime.h>
#include <hip/hip_bf16.h>

typedef __attribute__((ext_vector_type(4))) float f32x4;
typedef __attribute__((ext_vector_type(8))) __bf16 bf16x8;

#define NCTX 8192
#define DH 128
#define ROWE 4096                    /* floats between consecutive positions */
#define SC2 0.12751705766482797f     /* (1/sqrt(128)) * log2(e) */
#define KSTR 136                     /* bf16 row stride in staged buffers */
#define PSTR 40                      /* P lds row stride (shorts) */
#define OSTR 132                     /* O-bounce row stride (floats) */
#define BUFS (32*KSTR)               /* shorts per 8.5KB buffer */

__device__ __forceinline__ unsigned f2bf(float x) {
  union { float f; unsigned u; } un; un.f = x;
  return (un.u + 0x7FFFu + ((un.u >> 16) & 1u)) >> 16;   // RNE f32->bf16 bits
}
__device__ __forceinline__ unsigned pk2(float a, float b) {
  float2 t; t.x = a; t.y = b;
  union { __hip_bfloat162 h; unsigned u; } un;
  un.h = __float22bfloat162_rn(t);
  return un.u;
}

// Stage one 4096-float global row -> LDS bf16 [32][KSTR], fully coalesced.
// lane i loads consecutive float4 (1KB/instr, 8 fully-used 128B lines).
__device__ __forceinline__ void stage_row(const float* __restrict__ src,
                                          unsigned short* dst, int lane) {
  const int jb = lane >> 5, d = 4 * (lane & 31);
#pragma unroll
  for (int half = 0; half < 2; ++half) {
    f32x4 x[8];
#pragma unroll
    for (int ch = 0; ch < 8; ++ch)
      x[ch] = *reinterpret_cast<const f32x4*>(src + 4*lane + 256*(half*8 + ch));
#pragma unroll
    for (int ch = 0; ch < 8; ++ch) {
      const int j = jb + 2*(half*8 + ch);       // head row 0..31
      uint2 wv;
      wv.x = pk2(x[ch][0], x[ch][1]);
      wv.y = pk2(x[ch][2], x[ch][3]);
      *reinterpret_cast<uint2*>(&dst[j*KSTR + d]) = wv;
    }
  }
}

// One wave per position: 32(heads) x 32(heads) attention, d=128.
// All global access fully coalesced; fragment layouts built via LDS.
__global__ __launch_bounds__(256, 2) void hda(
    const float* __restrict__ q, const float* __restrict__ kg,
    const float* __restrict__ v, float* __restrict__ out)
{
  extern __shared__ __align__(16) unsigned short lds[];   // 8 bufs of BUFS shorts

  const int tid  = threadIdx.x;
  const int w    = tid >> 6;
  const int lane = tid & 63;
  const int c = lane & 15;    // frag row/col index
  const int g = lane >> 4;    // lane group 0..3

  const int pos = blockIdx.x * 4 + w;     // 0..16383
  const int b = pos >> 13;
  const int s = pos & (NCTX - 1);
  const int s0 = (blockIdx.x * 4) & (NCTX - 1);
  const bool shared_kv = (s0 >= 2048);    // then r = 8191 for the whole block

  const float* qb_ = q  + (size_t)b * NCTX * ROWE;
  const float* kb_ = kg + (size_t)b * NCTX * ROWE;
  const float* vb_ = v  + (size_t)b * NCTX * ROWE;
  float*       op  = out + ((size_t)b * NCTX + s) * ROWE;

  unsigned short* sb = lds + w * BUFS;    // per-wave stage buf (Q -> K -> P -> O)
  unsigned short* vbuf = shared_kv ? (lds + 5*BUFS) : (lds + (4 + w)*BUFS);
  const unsigned short* kbuf = shared_kv ? (lds + 4*BUFS) : sb;

  // ---- shared-KV blocks: cooperative one-time staging of K/V row 8191
  if (shared_kv) {
    const float* kr8 = kb_ + (size_t)(NCTX - 1) * ROWE;
    const float* vr8 = vb_ + (size_t)(NCTX - 1) * ROWE;
    const int d = 4 * (tid & 31), jb = tid >> 5;
#pragma unroll
    for (int ch = 0; ch < 4; ++ch) {
      const int fo = 4*tid + 1024*ch;
      const int j  = jb + 8*ch;
      f32x4 xk = *reinterpret_cast<const f32x4*>(kr8 + fo);
      f32x4 xv = *reinterpret_cast<const f32x4*>(vr8 + fo);
      uint2 wk, wv2;
      wk.x  = pk2(xk[0], xk[1]); wk.y  = pk2(xk[2], xk[3]);
      wv2.x = pk2(xv[0], xv[1]); wv2.y = pk2(xv[2], xv[3]);
      *reinterpret_cast<uint2*>(&lds[4*BUFS + j*KSTR + d]) = wk;
      *reinterpret_cast<uint2*>(&lds[5*BUFS + j*KSTR + d]) = wv2;
    }
    __syncthreads();
  }

  // ---- Q: stage own row -> frags
  stage_row(qb_ + (size_t)s * ROWE, sb, lane);
  bf16x8 qa[2][4];
#pragma unroll
  for (int t = 0; t < 2; ++t)
#pragma unroll
    for (int ks = 0; ks < 4; ++ks)
      qa[t][ks] = *reinterpret_cast<const bf16x8*>(&sb[(t*16 + c)*KSTR + ks*32 + g*8]);

  // ---- K: shared blocks read staged row; private blocks stage own (r = 4s)
  if (!shared_kv)
    stage_row(kb_ + (size_t)(4*s) * ROWE, sb, lane);
  bf16x8 kf[2][4];
#pragma unroll
  for (int t = 0; t < 2; ++t)
#pragma unroll
    for (int ks = 0; ks < 4; ++ks)
      kf[t][ks] = *reinterpret_cast<const bf16x8*>(&kbuf[(t*16 + c)*KSTR + ks*32 + g*8]);

  // ---- V: private blocks stage own row
  if (!shared_kv)
    stage_row(vb_ + (size_t)(4*s) * ROWE, vbuf, lane);

  // ---- S = Q K^T over heads: 4 16x16 tiles, K-dim 128
  f32x4 S[2][2];
#pragma unroll
  for (int it = 0; it < 2; ++it)
#pragma unroll
    for (int jt = 0; jt < 2; ++jt) {
      f32x4 acc = (f32x4)0.0f;
#pragma unroll
      for (int ks = 0; ks < 4; ++ks)
        acc = __builtin_amdgcn_mfma_f32_16x16x32_bf16(qa[it][ks], kf[jt][ks], acc, 0, 0, 0);
      S[it][jt] = acc;
    }

  // D-layout: S[it][jt][rr] = S_full[it*16+g*4+rr][jt*16+c]
  // ---- softmax over 32 cols (no max-sub: scores ~N(0,1), exp2 arg small)
  float p[2][2][4], inv[2][4];
#pragma unroll
  for (int it = 0; it < 2; ++it) {
    float ls[4] = {0.f, 0.f, 0.f, 0.f};
#pragma unroll
    for (int jt = 0; jt < 2; ++jt)
#pragma unroll
      for (int rr = 0; rr < 4; ++rr) {
        float e = exp2f(S[it][jt][rr] * SC2);
        p[it][jt][rr] = e;
        ls[rr] += e;
      }
#pragma unroll
    for (int m = 1; m <= 8; m <<= 1)
#pragma unroll
      for (int rr = 0; rr < 4; ++rr)
        ls[rr] += __shfl_xor(ls[rr], m);
#pragma unroll
    for (int rr = 0; rr < 4; ++rr) inv[it][rr] = 1.0f / ls[rr];
  }

  // ---- normalized P -> stage buf (row-major [i][j]), read back as A-frags
#pragma unroll
  for (int it = 0; it < 2; ++it)
#pragma unroll
    for (int jt = 0; jt < 2; ++jt)
#pragma unroll
      for (int rr = 0; rr < 4; ++rr)
        sb[(it*16 + g*4 + rr)*PSTR + jt*16 + c] =
            (unsigned short)f2bf(p[it][jt][rr] * inv[it][rr]);

  bf16x8 pa[2];   // lane holds P[it*16+c][g*8..+7]
  pa[0] = *reinterpret_cast<const bf16x8*>(&sb[c*PSTR + g*8]);
  pa[1] = *reinterpret_cast<const bf16x8*>(&sb[(16 + c)*PSTR + g*8]);

  // ---- V B-frags via LDS u16 gather: va[dt] lane (c,g) = V[g*8+j][dt*16+c]
  bf16x8 va[8];
#pragma unroll
  for (int dt = 0; dt < 8; ++dt) {
    unsigned t0 = vbuf[(g*8 + 0)*KSTR + dt*16 + c];
    unsigned t1 = vbuf[(g*8 + 1)*KSTR + dt*16 + c];
    unsigned t2 = vbuf[(g*8 + 2)*KSTR + dt*16 + c];
    unsigned t3 = vbuf[(g*8 + 3)*KSTR + dt*16 + c];
    unsigned t4 = vbuf[(g*8 + 4)*KSTR + dt*16 + c];
    unsigned t5 = vbuf[(g*8 + 5)*KSTR + dt*16 + c];
    unsigned t6 = vbuf[(g*8 + 6)*KSTR + dt*16 + c];
    unsigned t7 = vbuf[(g*8 + 7)*KSTR + dt*16 + c];
    union { unsigned u[4]; bf16x8 f; } un;
    un.u[0] = t0 | (t1 << 16); un.u[1] = t2 | (t3 << 16);
    un.u[2] = t4 | (t5 << 16); un.u[3] = t6 | (t7 << 16);
    va[dt] = un.f;
  }

  // ---- O^T = V^T P^T per it-half; bounce through LDS for coalesced stores
  float* ob = reinterpret_cast<float*>(sb);    // P already consumed
#pragma unroll
  for (int it = 0; it < 2; ++it) {
    f32x4 o[8];
#pragma unroll
    for (int dt = 0; dt < 8; ++dt)
      o[dt] = __builtin_amdgcn_mfma_f32_16x16x32_bf16(va[dt], pa[it], (f32x4)0.0f, 0, 0, 0);
    // D[g*4+rr][c] = O[it*16+c][dt*16+g*4+rr] -> LDS row c (head), col d
#pragma unroll
    for (int dt = 0; dt < 8; ++dt)
      *reinterpret_cast<f32x4*>(&ob[c*OSTR + dt*16 + g*4]) = o[dt];
    // coalesced flush: 8 full-line dwordx4 stores
#pragma unroll
    for (int ch = 0; ch < 8; ++ch) {
      const int flat = 4*lane + 256*ch;        // 0..2047
      const int row = flat >> 7, col = flat & 127;
      f32x4 y = *reinterpret_cast<const f32x4*>(&ob[row*OSTR + col]);
      *reinterpret_cast<f32x4*>(op + it*2048 + flat) = y;
    }
  }
}

extern "C" void kernel_launch(void* const* d_in, const int* in_sizes, int n_in,
                              void* d_out, int out_size, void* d_ws, size_t ws_size,
                              hipStream_t stream) {
  const float* q = (const float*)d_in[0];
  const float* k = (const float*)d_in[1];
  const float* v = (const float*)d_in[2];
  float* o = (float*)d_out;
  // 16384 positions (b=2 x s=8192), 4 waves/block -> 4096 blocks
  hda<<<dim3(4096, 1, 1), dim3(256, 1, 1), 8 * BUFS * 2, stream>>>(q, k, v, o);
}